// Round 12
// baseline (536.265 us; speedup 1.0000x reference)
//
#include <hip/hip_runtime.h>

typedef _Float16 half8  __attribute__((ext_vector_type(8)));
typedef __fp16   fp16x2 __attribute__((ext_vector_type(2)));   // cvt_pkrtz result type
typedef float    f32x4  __attribute__((ext_vector_type(4)));

#define LDS_BYTES (131072 + 16 + 256)   // teamA 64K | teamB 64K | sync[4] | tv[2][32]

__device__ __forceinline__ float rcpf(float x) { return __builtin_amdgcn_rcpf(x); }
__device__ __forceinline__ float sigf(float x)  { return rcpf(1.0f + __expf(-x)); }
__device__ __forceinline__ float tanhf_(float x){ return 1.0f - 2.0f * rcpf(1.0f + __expf(2.0f * x)); }

__device__ __forceinline__ half8 pk8(f32x4 lo, f32x4 hi) {
  union { half8 h; fp16x2 p[4]; } u;
  u.p[0] = __builtin_amdgcn_cvt_pkrtz(lo[0], lo[1]);
  u.p[1] = __builtin_amdgcn_cvt_pkrtz(lo[2], lo[3]);
  u.p[2] = __builtin_amdgcn_cvt_pkrtz(hi[0], hi[1]);
  u.p[3] = __builtin_amdgcn_cvt_pkrtz(hi[2], hi[3]);
  return u.h;
}

// ---------------- prepack: fp32 weights -> f16 MFMA-fragment granules in ws ----------------
// Gate granules (1 MiB @ wp+0): id = ((hb*16 + s)*4 + g), 1 KiB each.  Lane l byte l*16,
//   elem e = W[g*256 + hb*16 + (l&15)][s*32 + (l>>4)*8 + e]; K = 512 = [Wih | Whh].
// Decomp granules (128 KiB @ wp+1MiB): id = (hb*8 + s), value = Wd[k][h] (f16 hi; lo
//   correction from splitting cx, reusing the SAME B fragment for both passes).
__global__ __launch_bounds__(512) void prepack_kernel(
    const float* __restrict__ wih, const float* __restrict__ whh,
    const float* __restrict__ wd, char* __restrict__ wp)
{
  int idx = blockIdx.x * 512 + threadIdx.x;
  if (idx < 65536) {
    int n  = idx >> 6;
    int k8 = (idx & 63) << 3;
    const float* src = (k8 < 256) ? (wih + n * 256 + k8) : (whh + n * 256 + (k8 - 256));
    f32x4 v0 = *(const f32x4*)src;
    f32x4 v1 = *(const f32x4*)(src + 4);
    half8 hv;
#pragma unroll
    for (int e = 0; e < 4; ++e) { hv[e] = (_Float16)v0[e]; hv[e + 4] = (_Float16)v1[e]; }
    int g = n >> 8, h = n & 255;
    int gran = (((h >> 4) << 4) + (k8 >> 5)) * 4 + g;
    int lane = (h & 15) + (((k8 >> 3) & 3) << 4);
    *(half8*)(wp + (gran << 10) + (lane << 4)) = hv;
  } else {
    int i2 = idx - 65536;
    int h = i2 & 255, k = i2 >> 8;
    float v = wd[k * 256 + h];
    int gran = ((h >> 4) << 3) + (k >> 5);
    int lane = (h & 15) + (((k >> 3) & 3) << 4);
    *(_Float16*)(wp + (1 << 20) + (gran << 10) + (lane << 4) + ((k & 7) << 1)) = (_Float16)v;
  }
}

// ---------------- fused TA-LSTM cell: two anti-phase 8-wave teams per CU ----------------
// 256 blocks (1/CU, forced by 128K LDS) x 1024 thr.  Team t = waves t*8..t*8+7, own 64 KiB
// LDS half, processes 4 tiles of 32 rows x 256 h (R8's proven per-tile kernel).
// Sync: intra-team LDS-counter barrier (2 per tile); cross-team "turn" ticket serializes
// the HBM stage phases -> one team always stages while the other computes (HBM spread
// across the timeline instead of bursting between lockstep barriers).
__global__ __launch_bounds__(1024, 4) void talstm_kernel(
    const float* __restrict__ inp, const float* __restrict__ tt,
    const float* __restrict__ hx,  const float* __restrict__ cx,
    const float* __restrict__ bih, const float* __restrict__ bhh,
    const float* __restrict__ bd,  const char* __restrict__ wp,
    float* __restrict__ out)
{
  extern __shared__ __align__(16) char smem[];
  int*   syncp = (int*)(smem + 131072);        // [0]=turn, [1]=flagA, [2]=flagB
  float* tvb   = (float*)(smem + 131088);
  const int tid  = threadIdx.x;
  const int lane = tid & 63;
  const int wv   = __builtin_amdgcn_readfirstlane(tid >> 6);   // 0..15
  const int team = wv >> 3;
  const int w8   = wv & 7;
  const int l15  = lane & 15;
  const int kq8  = (lane >> 4) << 3;
  const int laneB = lane << 4;
  char*  sm  = smem + (team << 16);
  float* tvp = tvb + (team << 5);

  if (tid < 3) syncp[tid] = 0;
  __syncthreads();                             // only full-block barrier

  int barcnt = 0;
  auto teambar = [&]() {
    asm volatile("s_waitcnt lgkmcnt(0)" ::: "memory");
    ++barcnt;
    if (lane == 0)
      __hip_atomic_fetch_add(&syncp[1 + team], 1, __ATOMIC_RELAXED, __HIP_MEMORY_SCOPE_WORKGROUP);
    while (__hip_atomic_load(&syncp[1 + team], __ATOMIC_RELAXED, __HIP_MEMORY_SCOPE_WORKGROUP) < barcnt * 8)
      __builtin_amdgcn_s_sleep(2);
    asm volatile("" ::: "memory");
  };
  auto wait_turn = [&](int seq) {
    while (__hip_atomic_load(&syncp[0], __ATOMIC_RELAXED, __HIP_MEMORY_SCOPE_WORKGROUP) < seq)
      __builtin_amdgcn_s_sleep(2);
    asm volatile("" ::: "memory");
  };

#pragma unroll 1
  for (int j = 0; j < 4; ++j) {
    const int seq   = (j << 1) + team;
    const int rbase = (blockIdx.x << 8) + (j << 6) + (team << 5);   // 32-row tile

    // ---- stage phase (HBM): gated by the cross-team turn ticket ----
    wait_turn(seq);
    {
      const float* base = (w8 < 4) ? inp : hx;
      char* dst = sm + ((w8 < 4) ? 0 : 16384);
#pragma unroll
      for (int i = 0; i < 4; ++i) {
        int gid = ((w8 & 3) << 2) + i;         // 0..15: m = gid>>3, ss = gid&7
        int m = gid >> 3, ss = gid & 7;
        const float* p = base + (size_t)(rbase + (m << 4) + l15) * 256 + (ss << 5) + kq8;
        f32x4 v0 = *(const f32x4*)p, v1 = *(const f32x4*)(p + 4);
        *(half8*)(dst + (gid << 10) + laneB) = pk8(v0, v1);
      }
#pragma unroll
      for (int i = 0; i < 2; ++i) {            // cx: hi + lo split
        int c = (w8 << 1) + i;                 // 0..15
        int m = c >> 3, ss = c & 7;
        const float* p = cx + (size_t)(rbase + (m << 4) + l15) * 256 + (ss << 5) + kq8;
        f32x4 v0 = *(const f32x4*)p, v1 = *(const f32x4*)(p + 4);
        half8 hv = pk8(v0, v1);
        f32x4 l0, l1;
#pragma unroll
        for (int e = 0; e < 4; ++e) {
          l0[e] = v0[e] - (float)hv[e];
          l1[e] = v1[e] - (float)hv[e + 4];
        }
        *(half8*)(sm + 32768 + (c << 10) + laneB) = hv;
        *(half8*)(sm + 49152 + (c << 10) + laneB) = pk8(l0, l1);
      }
      if (w8 == 0 && lane < 32) tvp[lane] = tt[rbase + lane];
    }
    teambar();                                 // team data staged & visible
    if (w8 == 0 && lane == 0)                  // release the HBM turn to the other team
      __hip_atomic_store(&syncp[0], seq + 1, __ATOMIC_RELAXED, __HIP_MEMORY_SCOPE_WORKGROUP);

    // ---- gate passes: hb = 2*w8, 2*w8+1 sequentially (liveness small, R8-proven) ----
    half8 pk_ig[2], pk_f[2], pk_o[2];
#pragma unroll
    for (int hb2 = 0; hb2 < 2; ++hb2) {
      const int hb = (w8 << 1) + hb2;
      const int h  = (hb << 4) + l15;
      const float bi  = bih[h]       + bhh[h];
      const float bfg = bih[256 + h] + bhh[256 + h];
      const float bg  = bih[512 + h] + bhh[512 + h];
      const float bo  = bih[768 + h] + bhh[768 + h];

      f32x4 acc[4][2];
      const f32x4 fz = {0.f, 0.f, 0.f, 0.f};
#pragma unroll
      for (int g = 0; g < 4; ++g) { acc[g][0] = fz; acc[g][1] = fz; }

      const char* wgp = wp + (hb << 16) + laneB;
      half8 nb0 = *(const half8*)(wgp);
      half8 nb1 = *(const half8*)(wgp + 1024);
      half8 nb2 = *(const half8*)(wgp + 2048);
      half8 nb3 = *(const half8*)(wgp + 3072);

#pragma unroll
      for (int s = 0; s < 16; ++s) {
        half8 b0 = nb0, b1 = nb1, b2 = nb2, b3 = nb3;
        if (s < 15) {
          const char* p = wgp + ((s + 1) << 12);
          nb0 = *(const half8*)(p);
          nb1 = *(const half8*)(p + 1024);
          nb2 = *(const half8*)(p + 2048);
          nb3 = *(const half8*)(p + 3072);
        }
        const int so = ((s >> 3) << 14) + ((s & 7) << 10);   // sec 16K | ss 1K
#pragma unroll
        for (int m = 0; m < 2; ++m) {
          half8 a = *(const half8*)(sm + so + (m << 13) + laneB);
          acc[0][m] = __builtin_amdgcn_mfma_f32_16x16x32_f16(a, b0, acc[0][m], 0, 0, 0);
          acc[1][m] = __builtin_amdgcn_mfma_f32_16x16x32_f16(a, b1, acc[1][m], 0, 0, 0);
          acc[2][m] = __builtin_amdgcn_mfma_f32_16x16x32_f16(a, b2, acc[2][m], 0, 0, 0);
          acc[3][m] = __builtin_amdgcn_mfma_f32_16x16x32_f16(a, b3, acc[3][m], 0, 0, 0);
        }
      }
#pragma unroll
      for (int m = 0; m < 2; ++m)
#pragma unroll
        for (int e = 0; e < 4; ++e) {
          const int ve = (m << 2) + e;
          pk_ig[hb2][ve] = (_Float16)(sigf(acc[0][m][e] + bi) * tanhf_(acc[2][m][e] + bg));
          pk_f[hb2][ve]  = (_Float16)(sigf(acc[1][m][e] + bfg));
          pk_o[hb2][ve]  = (_Float16)(sigf(acc[3][m][e] + bo));
        }
    }

    // ---- decomp pass: both hb together (hi+lo share the b fragment) ----
    f32x4 accd[2][2];
    {
      const f32x4 fz = {0.f, 0.f, 0.f, 0.f};
      accd[0][0] = fz; accd[0][1] = fz; accd[1][0] = fz; accd[1][1] = fz;
      const char* wd0 = wp + (1 << 20) + ((w8 << 1) << 13) + laneB;
      const char* wd1 = wd0 + 8192;
      half8 nd0 = *(const half8*)(wd0);
      half8 nd1 = *(const half8*)(wd1);
#pragma unroll
      for (int s = 0; s < 8; ++s) {
        half8 b0 = nd0, b1 = nd1;
        if (s < 7) {
          nd0 = *(const half8*)(wd0 + ((s + 1) << 10));
          nd1 = *(const half8*)(wd1 + ((s + 1) << 10));
        }
#pragma unroll
        for (int m = 0; m < 2; ++m) {
          half8 ah = *(const half8*)(sm + 32768 + (m << 13) + (s << 10) + laneB);
          half8 al = *(const half8*)(sm + 49152 + (m << 13) + (s << 10) + laneB);
          accd[0][m] = __builtin_amdgcn_mfma_f32_16x16x32_f16(ah, b0, accd[0][m], 0, 0, 0);
          accd[0][m] = __builtin_amdgcn_mfma_f32_16x16x32_f16(al, b0, accd[0][m], 0, 0, 0);
          accd[1][m] = __builtin_amdgcn_mfma_f32_16x16x32_f16(ah, b1, accd[1][m], 0, 0, 0);
          accd[1][m] = __builtin_amdgcn_mfma_f32_16x16x32_f16(al, b1, accd[1][m], 0, 0, 0);
        }
      }
    }

    // ---- epilogue ----
    const int er = (lane >> 4) << 2;
#pragma unroll
    for (int hb2 = 0; hb2 < 2; ++hb2) {
      const int hb = (w8 << 1) + hb2;
      const int h  = (hb << 4) + l15;
      const float bdv = bd[h];
      const int hoff = ((hb >> 1) << 10) + ((((hb & 1) << 1) + (l15 >> 3)) << 8) + ((l15 & 7) << 1);
#pragma unroll
      for (int m = 0; m < 2; ++m) {
        float* po = out + (size_t)(rbase + (m << 4) + er) * 256 + h;
        const char* chp = sm + 32768 + (m << 13) + (er << 4) + hoff;
#pragma unroll
        for (int e = 0; e < 4; ++e) {
          const int ve = (m << 2) + e;
          const float tv = tvp[(m << 4) + er + e];
          const float T  = (tv != 0.0f) ? rcpf(tv) : 0.0f;
          const float cxv = (float)*(const _Float16*)(chp + (e << 4))
                          + (float)*(const _Float16*)(chp + 16384 + (e << 4));
          const float cst = tanhf_(accd[hb2][m][e] + bdv);
          const float cxa = cxv - cst + T * cst;
          const float cy  = (float)pk_f[hb2][ve] * cxa + (float)pk_ig[hb2][ve];
          const float hy  = (float)pk_o[hb2][ve] * tanhf_(cy);
          po[(size_t)e * 256]               = hy;
          po[16777216ull + (size_t)e * 256] = cy;
        }
      }
    }
    teambar();                               // team done reading P/Q -> next stage may overwrite
  }
}

extern "C" void kernel_launch(void* const* d_in, const int* in_sizes, int n_in,
                              void* d_out, int out_size, void* d_ws, size_t ws_size,
                              hipStream_t stream) {
  const float* inp = (const float*)d_in[0];
  const float* t   = (const float*)d_in[1];
  const float* hx  = (const float*)d_in[2];
  const float* cx  = (const float*)d_in[3];
  const float* wih = (const float*)d_in[4];
  const float* whh = (const float*)d_in[5];
  const float* bih = (const float*)d_in[6];
  const float* bhh = (const float*)d_in[7];
  const float* wd  = (const float*)d_in[8];
  const float* bd  = (const float*)d_in[9];
  float* out = (float*)d_out;
  char* wp = (char*)d_ws;   // 1.125 MiB: 1 MiB gate granules + 128 KiB decomp granules

  prepack_kernel<<<256, 512, 0, stream>>>(wih, whh, wd, wp);

  hipFuncSetAttribute((const void*)talstm_kernel,
                      hipFuncAttributeMaxDynamicSharedMemorySize, LDS_BYTES);
  talstm_kernel<<<256, 1024, LDS_BYTES, stream>>>(inp, t, hx, cx, bih, bhh, bd, wp, out);
}